// Round 6
// baseline (766.142 us; speedup 1.0000x reference)
//
#include <hip/hip_runtime.h>
#include <math.h>

#define GG 512
#define TT 25
#define PP 10
#define MM 5
#define EE 32
#define HID 32
#define HH 128
#define NEDGE 40
#define NGRAPH (GG*TT)          // 12800
#define NTOT (GG*TT*PP)         // 128000

typedef __attribute__((ext_vector_type(8))) short short8v;
typedef __attribute__((ext_vector_type(4))) short short4v;
typedef __attribute__((ext_vector_type(4))) float f32x4;

// A-panel LDS index: [s][ki<6][mt<2][lane<64][e<8] (shorts)
#define AIDX(s,ki,mt,l) (((((s)*6+(ki))*2+(mt))*64+(l))*8)
#define WB_PER_T 196608   // 2*6*32*64*8

__device__ __forceinline__ unsigned short f2bf(float x){
    unsigned u = __float_as_uint(x);
    u += 0x7fffu + ((u >> 16) & 1u);
    return (unsigned short)(u >> 16);
}
__device__ __forceinline__ float bf2f(unsigned short s){
    return __uint_as_float(((unsigned)s) << 16);
}
__device__ __forceinline__ float sigm(float x){ return 1.f/(1.f+__expf(-x)); }
__device__ __forceinline__ float tanh_fast(float x){
    float ax = fabsf(x);
    float e  = __expf(-2.f*ax);
    float t  = (1.f-e)/(1.f+e);
    return copysignf(t, x);
}

// ---------------------------------------------------------------------------
// Prep: build MFMA-fragment weight tensor wB[t][s][ki][nt][lane][e] (bf16 bits)
// ---------------------------------------------------------------------------
__global__ void prep_kernel(const float* __restrict__ W_ih, const float* __restrict__ W_hh,
                            const float* __restrict__ b_ih, const float* __restrict__ b_hh,
                            short* __restrict__ wB, float* __restrict__ wadd,
                            float* __restrict__ bsum)
{
    const int NW = TT*WB_PER_T;          // 4,915,200
    const int NA = TT*2*512;             // 25,600
    const int NB = TT*512;               // 12,800
    for (int idx = blockIdx.x*blockDim.x + threadIdx.x; idx < NW+NA+NB;
         idx += gridDim.x*blockDim.x) {
        if (idx < NW) {
            int e  = idx & 7;
            int l  = (idx >> 3) & 63;
            int nt = (idx >> 9) & 31;
            int rest = idx >> 14;        // (t*2+s)*6 + ki
            int ki = rest % 6; rest /= 6;
            int s  = rest & 1;
            int t  = rest >> 1;
            int k  = ki*32 + (l >> 4)*8 + e;
            int n  = nt*16 + (l & 15);
            float wv = (k < 128) ? W_hh[(size_t)(t*512 + n)*128 + k]
                                 : W_ih[(size_t)(t*512 + n)*66 + (k - 128)];
            unsigned short hi = f2bf(wv);
            unsigned short outv = (s == 0) ? hi : f2bf(wv - bf2f(hi));
            wB[idx] = (short)outv;
        } else if (idx < NW + NA) {
            int i2 = idx - NW;
            int t = i2 / 1024, r = i2 % 1024;
            int cc = r >> 9, n = r & 511;
            wadd[i2] = W_ih[(size_t)(t*512 + n)*66 + 64 + cc];
        } else {
            int i3 = idx - NW - NA;
            bsum[i3] = b_ih[i3] + b_hh[i3];
        }
    }
}

// ---------------------------------------------------------------------------
// Graph kernel v3: one 64-thread block per (g,t) vote graph.
// All seg_means moved to the OTHER side of the GEMMs: Adj@(H@W) = (Adj@H)@W.
// No Sm/Sagg buffers; 4 aggregated super-buckets + self per output sign,
// each via a tiny Y[10][32] LDS buffer. LDS ~9.4 KB for occupancy.
// ---------------------------------------------------------------------------
__device__ __forceinline__ void gemm32(const float* __restrict__ A,
                                       const float* __restrict__ W,
                                       float (&acc)[10][4], int kp, int c0)
{
#pragma unroll
    for (int kb = 0; kb < 2; ++kb) {
        const float* wr = W + (kp + 4*kb)*32 + c0;
        float4 w0 = *(const float4*)(wr);
        float4 w1 = *(const float4*)(wr + 32);
        float4 w2 = *(const float4*)(wr + 64);
        float4 w3 = *(const float4*)(wr + 96);
#pragma unroll
        for (int n = 0; n < 10; ++n) {
            float4 f = *(const float4*)(A + n*32 + kp + 4*kb);
            acc[n][0] += f.x*w0.x + f.y*w1.x + f.z*w2.x + f.w*w3.x;
            acc[n][1] += f.x*w0.y + f.y*w1.y + f.z*w2.y + f.w*w3.y;
            acc[n][2] += f.x*w0.z + f.y*w1.z + f.z*w2.z + f.w*w3.z;
            acc[n][3] += f.x*w0.w + f.y*w1.w + f.z*w2.w + f.w*w3.w;
        }
    }
}

__device__ __forceinline__ void gemm64(const float* __restrict__ A,
                                       const float* __restrict__ W,
                                       float (&acc)[10][4], int kp, int c0)
{
#pragma unroll
    for (int kb = 0; kb < 4; ++kb) {
        const float* wr = W + (kp + 4*kb)*32 + c0;
        float4 w0 = *(const float4*)(wr);
        float4 w1 = *(const float4*)(wr + 32);
        float4 w2 = *(const float4*)(wr + 64);
        float4 w3 = *(const float4*)(wr + 96);
#pragma unroll
        for (int n = 0; n < 10; ++n) {
            float4 f = *(const float4*)(A + n*64 + kp + 4*kb);
            acc[n][0] += f.x*w0.x + f.y*w1.x + f.z*w2.x + f.w*w3.x;
            acc[n][1] += f.x*w0.y + f.y*w1.y + f.z*w2.y + f.w*w3.y;
            acc[n][2] += f.x*w0.z + f.y*w1.z + f.z*w2.z + f.w*w3.z;
            acc[n][3] += f.x*w0.w + f.y*w1.w + f.z*w2.w + f.w*w3.w;
        }
    }
}

#define REDUCE1016(acc) \
    _Pragma("unroll") for (int n=0;n<10;++n) \
    _Pragma("unroll") for (int q=0;q<4;++q) { \
        float v = acc[n][q]; v += __shfl_xor(v,8); v += __shfl_xor(v,16); acc[n][q]=v; }

__global__ __launch_bounds__(64) void graph_kernel(
    const float* __restrict__ x0,
    const float* __restrict__ Wb_pos, const float* __restrict__ bb_pos,
    const float* __restrict__ Wb_neg, const float* __restrict__ bb_neg,
    const float* __restrict__ Wd_pos, const float* __restrict__ bd_pos,
    const float* __restrict__ Wd_neg, const float* __restrict__ bd_neg,
    const int* __restrict__ pos_src, const int* __restrict__ pos_dst,
    const int* __restrict__ neg_src, const int* __restrict__ neg_dst,
    float* __restrict__ emb)
{
    __shared__ float Sx[10][64];        // 2560 B
    __shared__ float Sh[2][10][32];     // 2560 B
    __shared__ float Yb[2][10][32];     // 2560 B (overlaid: Cm 200 f32 + Ses 160 i32)
    __shared__ float Adj[4][10][10];    // 1600 B
    __shared__ float Scnt[4][10];       //  160 B   total 9440 B
    float* CmP  = &Yb[0][0][0];         // [2][10][10] = 200 floats
    int*   SesP = (int*)(&Yb[0][0][0] + 200);  // [4][40] = 160 ints

    const int gid = blockIdx.x;
    const int nb  = gid * PP;
    const int tid = threadIdx.x;

    // stage x (float4) + edges, zero Cm
    for (int i = tid; i < 160; i += 64)
        ((float4*)Sx)[i] = ((const float4*)x0)[nb*16 + i];
    for (int i = tid; i < 160; i += 64) {
        int b = i / 40, e = i % 40;
        const int* p = (b==0)?pos_src:(b==1)?pos_dst:(b==2)?neg_src:neg_dst;
        SesP[i] = p[gid*40 + e];
    }
    if (tid < 40) {          // zero Cm (200 floats; 64 threads not needed)
        CmP[tid] = 0.f; CmP[tid+40] = 0.f; CmP[tid+80] = 0.f;
        CmP[tid+120] = 0.f; CmP[tid+160] = 0.f;
    }
    __syncthreads();
    if (tid < 40) {
        atomicAdd(&CmP[SesP[tid]*10      + SesP[40 + tid]],  1.f);
        atomicAdd(&CmP[100 + SesP[80 + tid]*10 + SesP[120 + tid]], 1.f);
    }
    __syncthreads();
    if (tid < 40) {
        int b = tid / 10, n = tid % 10;
        int si = b >> 1, isCol = b & 1;
        float s = 0.f;
        for (int m = 0; m < 10; ++m)
            s += isCol ? CmP[si*100 + m*10 + n] : CmP[si*100 + n*10 + m];
        Scnt[b][n] = fmaxf(s, 1.f);
    }
    __syncthreads();
    for (int i = tid; i < 400; i += 64) {
        int a = i / 100, r = i % 100, n = r / 10, m = r % 10;
        int si = a >> 1, isOut = a & 1;
        float cv = isOut ? CmP[si*100 + m*10 + n] : CmP[si*100 + n*10 + m];
        Adj[a][n][m] = cv / Scnt[si*2 + isOut][n];
    }
    __syncthreads();   // Adj ready; Cm/Ses dead -> Yb free

    const int sign = tid >> 5;
    const int g4   = (tid >> 3) & 3;
    const int l8   = tid & 7;
    const int c0   = 4*l8;
    const int kp8  = g4*8;
    const int kp16 = g4*16;
    const int m0   = (g4*10) >> 2;        // 0,2,5,7
    const int m1   = ((g4+1)*10) >> 2;    // 2,5,7,10

    // =================== base layer ===================
    {
        const float* Wb = sign ? Wb_neg : Wb_pos;
        float acc2[10][4];
#pragma unroll
        for (int n=0;n<10;++n){acc2[n][0]=0;acc2[n][1]=0;acc2[n][2]=0;acc2[n][3]=0;}
        gemm64(&Sx[0][0], Wb + 64*32, acc2, kp16, c0);   // self part (x)
        float acc[10][4];
#pragma unroll
        for (int n=0;n<10;++n){acc[n][0]=0;acc[n][1]=0;acc[n][2]=0;acc[n][3]=0;}
        gemm64(&Sx[0][0], Wb, acc, kp16, c0);            // mean part pre-Adj
        REDUCE1016(acc)
        if (g4 == 0)
#pragma unroll
            for (int n=0;n<10;++n)
                *(float4*)&Yb[sign][n][c0] = (float4){acc[n][0],acc[n][1],acc[n][2],acc[n][3]};
        __syncthreads();
        {
            const int a = 2*sign;      // Apin / Anin
            for (int m = m0; m < m1; ++m) {
                float4 y = *(const float4*)&Yb[sign][m][c0];
#pragma unroll
                for (int n = 0; n < 10; ++n) {
                    float w = Adj[a][n][m];
                    acc2[n][0] += w*y.x; acc2[n][1] += w*y.y;
                    acc2[n][2] += w*y.z; acc2[n][3] += w*y.w;
                }
            }
        }
        REDUCE1016(acc2)
        {
            const float* bb = sign ? bb_neg : bb_pos;
            float4 b4 = *(const float4*)(bb + c0);
#pragma unroll
            for (int n=0;n<10;++n) {
                float v0=acc2[n][0]+b4.x, v1=acc2[n][1]+b4.y,
                      v2=acc2[n][2]+b4.z, v3=acc2[n][3]+b4.w;
                float s = v0*v0+v1*v1+v2*v2+v3*v3;
                s += __shfl_xor(s,1); s += __shfl_xor(s,2); s += __shfl_xor(s,4);
                float rn = 1.f / fmaxf(sqrtf(s), 1e-12f);
                acc2[n][0]=v0*rn; acc2[n][1]=v1*rn; acc2[n][2]=v2*rn; acc2[n][3]=v3*rn;
            }
        }
        __syncthreads();   // Yb reads done (already), ensure ordering before Sh write
        if (g4 == 0)
#pragma unroll
            for (int n=0;n<10;++n)
                *(float4*)&Sh[sign][n][c0] = (float4){acc2[n][0],acc2[n][1],acc2[n][2],acc2[n][3]};
        __syncthreads();
    }

    // =================== two deep layers ===================
    for (int l = 0; l < 2; ++l) {
        const float* Wd = (sign ? Wd_neg : Wd_pos) + l*7168;
        const float* Hs = &Sh[sign][0][0];
        const float* Ho = &Sh[1-sign][0][0];
        float acc2[10][4];
#pragma unroll
        for (int n=0;n<10;++n){acc2[n][0]=0;acc2[n][1]=0;acc2[n][2]=0;acc2[n][3]=0;}
        gemm32(Hs, Wd + 160*32, acc2, kp8, c0);          // self hp/hn part
        gemm32(Ho, Wd + 192*32, acc2, kp8, c0);

        const int adjIdx[4] = {2*sign, 2*sign+1, 2-2*sign, 3-2*sign};
#pragma unroll
        for (int b = 0; b < 4; ++b) {
            float acc[10][4];
#pragma unroll
            for (int n=0;n<10;++n){acc[n][0]=0;acc[n][1]=0;acc[n][2]=0;acc[n][3]=0;}
            const float* Ab = (b < 2) ? Hs : Ho;
            gemm32(Ab, Wd + (b*32)*32, acc, kp8, c0);
            if (b == 0) gemm32(Ho, Wd + 128*32, acc, kp8, c0);   // merged 5th part
            REDUCE1016(acc)
            if (g4 == 0)
#pragma unroll
                for (int n=0;n<10;++n)
                    *(float4*)&Yb[sign][n][c0] = (float4){acc[n][0],acc[n][1],acc[n][2],acc[n][3]};
            __syncthreads();
            {
                const int a = adjIdx[b];
                for (int m = m0; m < m1; ++m) {
                    float4 y = *(const float4*)&Yb[sign][m][c0];
#pragma unroll
                    for (int n = 0; n < 10; ++n) {
                        float w = Adj[a][n][m];
                        acc2[n][0] += w*y.x; acc2[n][1] += w*y.y;
                        acc2[n][2] += w*y.z; acc2[n][3] += w*y.w;
                    }
                }
            }
            __syncthreads();   // Yb reusable
        }
        REDUCE1016(acc2)
        {
            const float* bd = (sign ? bd_neg : bd_pos) + l*32;
            float4 b4 = *(const float4*)(bd + c0);
#pragma unroll
            for (int n=0;n<10;++n) {
                float v0=acc2[n][0]+b4.x, v1=acc2[n][1]+b4.y,
                      v2=acc2[n][2]+b4.z, v3=acc2[n][3]+b4.w;
                float s = v0*v0+v1*v1+v2*v2+v3*v3;
                s += __shfl_xor(s,1); s += __shfl_xor(s,2); s += __shfl_xor(s,4);
                float rn = 1.f / fmaxf(sqrtf(s), 1e-12f);
                acc2[n][0]=v0*rn; acc2[n][1]=v1*rn; acc2[n][2]=v2*rn; acc2[n][3]=v3*rn;
            }
        }
        __syncthreads();   // all Sh reads of this layer complete
        if (g4 == 0)
#pragma unroll
            for (int n=0;n<10;++n)
                *(float4*)&Sh[sign][n][c0] = (float4){acc2[n][0],acc2[n][1],acc2[n][2],acc2[n][3]};
        __syncthreads();
    }

#pragma unroll
    for (int n = 0; n < 10; ++n) {
        float v = (tid < 32) ? Sh[0][n][tid] : Sh[1][n][tid-32];
        emb[(nb+n)*64 + tid] = v;
    }
}

// ---------------------------------------------------------------------------
// Persistent MFMA LSTM (unchanged from round 4/5).
// ---------------------------------------------------------------------------
__global__ __launch_bounds__(512) void lstm_mfma(
    const float* __restrict__ emb, const float* __restrict__ add_info,
    const short* __restrict__ wB, const float* __restrict__ wadd,
    const float* __restrict__ bsum, const float* __restrict__ hx0,
    const float* __restrict__ cx0, float* __restrict__ hbuf)
{
    __shared__ short aP[12288];          // [2][6][2][64][8] bf16 bits, 24.6 KB
    __shared__ float Sadd[2][32][2];
    const int tid = threadIdx.x;
    const int w  = tid >> 6;             // wave 0..7
    const int l  = tid & 63;
    const int li = l & 15;
    const int lk = l >> 4;
    const int R0 = blockIdx.x * 32;

    {
        int row = tid >> 4, j0 = (tid & 15) * 8;
        const float* hp = hx0 + (size_t)(R0 + row)*128 + j0;
        float4 h0 = *(const float4*)hp;
        float4 h1 = *(const float4*)(hp + 4);
        float v[8] = {h0.x,h0.y,h0.z,h0.w,h1.x,h1.y,h1.z,h1.w};
        short8v hi, lo;
#pragma unroll
        for (int e = 0; e < 8; ++e) {
            unsigned short hs = f2bf(v[e]);
            hi[e] = (short)hs;
            lo[e] = (short)f2bf(v[e] - bf2f(hs));
        }
        int mt = row >> 4, ln = (row & 15) + 16*((j0 >> 3) & 3), ki = j0 >> 5;
        *(short8v*)&aP[AIDX(0,ki,mt,ln)] = hi;
        *(short8v*)&aP[AIDX(1,ki,mt,ln)] = lo;
    }
    {
        int row = tid >> 4, d0 = (tid & 15)*4;
        int R = R0 + row, g = R/10, p = R - 10*g;
        float4 f = *(const float4*)&emb[((size_t)(g*TT + 0)*PP + p)*64 + d0];
        int k0 = 128 + d0;
        int mt = row>>4, ln = (row&15) + 16*((k0>>3)&3), ki = k0>>5, e0 = k0&7;
        float v[4] = {f.x,f.y,f.z,f.w};
        short4v hi, lo;
#pragma unroll
        for (int e = 0; e < 4; ++e) {
            unsigned short hs = f2bf(v[e]);
            hi[e] = (short)hs;
            lo[e] = (short)f2bf(v[e] - bf2f(hs));
        }
        *(short4v*)&aP[AIDX(0,ki,mt,ln)+e0] = hi;
        *(short4v*)&aP[AIDX(1,ki,mt,ln)+e0] = lo;
    }
    if (tid < 64) {
        int row = tid >> 1, cc = tid & 1;
        int R = R0 + row, g = R/10, p = R - 10*g;
        Sadd[0][row][cc] = add_info[((size_t)(g*MM + 0)*PP + p)*2 + cc];
    }
    float c[2][4];
#pragma unroll
    for (int mt = 0; mt < 2; ++mt)
#pragma unroll
        for (int r = 0; r < 4; ++r) {
            int row = mt*16 + lk*4 + r;
            c[mt][r] = cx0[(size_t)(R0+row)*128 + 16*w + li];
        }
    __syncthreads();

    for (int t = 0; t < TT; ++t) {
        f32x4 acc[2][4];
#pragma unroll
        for (int g = 0; g < 4; ++g) {
            float bs = bsum[t*512 + 128*g + 16*w + li];
            acc[0][g] = (f32x4){bs,bs,bs,bs};
            acc[1][g] = (f32x4){bs,bs,bs,bs};
        }
        const short* wt = wB + (size_t)t * WB_PER_T;
#pragma unroll 2
        for (int ki = 0; ki < 6; ++ki) {
            short8v ah0 = *(const short8v*)&aP[AIDX(0,ki,0,l)];
            short8v ah1 = *(const short8v*)&aP[AIDX(0,ki,1,l)];
            short8v al0 = *(const short8v*)&aP[AIDX(1,ki,0,l)];
            short8v al1 = *(const short8v*)&aP[AIDX(1,ki,1,l)];
#pragma unroll
            for (int g = 0; g < 4; ++g) {
                int nt = w + 8*g;
                short8v bh = *(const short8v*)(wt + (((size_t)ki*32 + nt)*64 + l)*8);
                short8v bl = *(const short8v*)(wt + (((size_t)(6+ki)*32 + nt)*64 + l)*8);
                acc[0][g] = __builtin_amdgcn_mfma_f32_16x16x32_bf16(ah0, bh, acc[0][g], 0, 0, 0);
                acc[0][g] = __builtin_amdgcn_mfma_f32_16x16x32_bf16(ah0, bl, acc[0][g], 0, 0, 0);
                acc[0][g] = __builtin_amdgcn_mfma_f32_16x16x32_bf16(al0, bh, acc[0][g], 0, 0, 0);
                acc[1][g] = __builtin_amdgcn_mfma_f32_16x16x32_bf16(ah1, bh, acc[1][g], 0, 0, 0);
                acc[1][g] = __builtin_amdgcn_mfma_f32_16x16x32_bf16(ah1, bl, acc[1][g], 0, 0, 0);
                acc[1][g] = __builtin_amdgcn_mfma_f32_16x16x32_bf16(al1, bh, acc[1][g], 0, 0, 0);
            }
        }
        __syncthreads();

        float wa0[4], wa1[4];
#pragma unroll
        for (int g = 0; g < 4; ++g) {
            wa0[g] = wadd[(size_t)(t*2+0)*512 + 128*g + 16*w + li];
            wa1[g] = wadd[(size_t)(t*2+1)*512 + 128*g + 16*w + li];
        }
        const int sb = t & 1;
        const int j  = 16*w + li;
        const int jsh = 16*((j >> 3) & 3);
        const int jki = j >> 5;
        const int je  = j & 7;
#pragma unroll
        for (int mt = 0; mt < 2; ++mt) {
#pragma unroll
            for (int r = 0; r < 4; ++r) {
                int row = mt*16 + lk*4 + r;
                float ad0 = Sadd[sb][row][0], ad1 = Sadd[sb][row][1];
                float v0 = acc[mt][0][r] + ad0*wa0[0] + ad1*wa1[0];
                float v1 = acc[mt][1][r] + ad0*wa0[1] + ad1*wa1[1];
                float v2 = acc[mt][2][r] + ad0*wa0[2] + ad1*wa1[2];
                float v3 = acc[mt][3][r] + ad0*wa0[3] + ad1*wa1[3];
                float iv = sigm(v0);
                float fv = sigm(v1);
                float gv = tanh_fast(v2);
                float ov = sigm(v3);
                float cn = fv*c[mt][r] + iv*gv;
                c[mt][r] = cn;
                float hv = ov*tanh_fast(cn);
                unsigned short hs = f2bf(hv);
                int ln = (row & 15) + jsh;
                aP[AIDX(0, jki, mt, ln) + je] = (short)hs;
                aP[AIDX(1, jki, mt, ln) + je] = (short)f2bf(hv - bf2f(hs));
                if (t == TT-1) hbuf[(size_t)(R0+row)*128 + j] = hv;
            }
        }
        if (t < TT-1) {
            int row = tid >> 4, d0 = (tid & 15)*4;
            int R = R0 + row, g = R/10, p = R - 10*g;
            float4 f = *(const float4*)&emb[((size_t)(g*TT + (t+1))*PP + p)*64 + d0];
            int k0 = 128 + d0;
            int mt = row>>4, ln = (row&15) + 16*((k0>>3)&3), ki = k0>>5, e0 = k0&7;
            float v[4] = {f.x,f.y,f.z,f.w};
            short4v hi, lo;
#pragma unroll
            for (int e = 0; e < 4; ++e) {
                unsigned short hs = f2bf(v[e]);
                hi[e] = (short)hs;
                lo[e] = (short)f2bf(v[e] - bf2f(hs));
            }
            *(short4v*)&aP[AIDX(0,ki,mt,ln)+e0] = hi;
            *(short4v*)&aP[AIDX(1,ki,mt,ln)+e0] = lo;
            if (tid < 64) {
                int rw = tid >> 1, cc = tid & 1;
                int R2 = R0 + rw, g2 = R2/10, p2 = R2 - 10*g2;
                Sadd[sb^1][rw][cc] =
                    add_info[((size_t)(g2*MM + (t+1)/MM)*PP + p2)*2 + cc];
            }
        }
        __syncthreads();
    }
}

// ---------------------------------------------------------------------------
// Final projection: out = h_last @ Wf + bf
// ---------------------------------------------------------------------------
__global__ __launch_bounds__(256) void final_proj(
    const float* __restrict__ hbuf, const float* __restrict__ Wf,
    const float* __restrict__ bf, float* __restrict__ out)
{
    __shared__ float wl[128*32];
    __shared__ float hl[64][128];
    const int tid = threadIdx.x;
    const int row0 = blockIdx.x * 64;
    for (int i = tid; i < 4096; i += 256) wl[i] = Wf[i];
    for (int i = tid; i < 8192; i += 256) hl[i>>7][i&127] = hbuf[row0*128 + i];
    __syncthreads();
    const int e  = tid & 31;
    const int rg = tid >> 5;
    float b = bf[e];
    float acc[8];
#pragma unroll
    for (int r=0;r<8;++r) acc[r] = b;
    for (int k = 0; k < 128; ++k) {
        float ww = wl[k*32 + e];
#pragma unroll
        for (int r=0;r<8;++r) acc[r] += hl[rg*8+r][k]*ww;
    }
#pragma unroll
    for (int r=0;r<8;++r) out[(row0 + rg*8 + r)*32 + e] = acc[r];
}

// ---------------------------------------------------------------------------
extern "C" void kernel_launch(void* const* d_in, const int* in_sizes, int n_in,
                              void* d_out, int out_size, void* d_ws, size_t ws_size,
                              hipStream_t stream)
{
    const float* x0       = (const float*)d_in[0];
    const float* add_info = (const float*)d_in[1];
    const float* Wb_pos   = (const float*)d_in[2];
    const float* bb_pos   = (const float*)d_in[3];
    const float* Wb_neg   = (const float*)d_in[4];
    const float* bb_neg   = (const float*)d_in[5];
    const float* Wd_pos   = (const float*)d_in[6];
    const float* bd_pos   = (const float*)d_in[7];
    const float* Wd_neg   = (const float*)d_in[8];
    const float* bd_neg   = (const float*)d_in[9];
    const float* W_ih     = (const float*)d_in[10];
    const float* W_hh     = (const float*)d_in[11];
    const float* b_ih     = (const float*)d_in[12];
    const float* b_hh     = (const float*)d_in[13];
    const float* hx0      = (const float*)d_in[14];
    const float* cx0      = (const float*)d_in[15];
    const float* Wf       = (const float*)d_in[16];
    const float* bf       = (const float*)d_in[17];
    const int*   pos_src  = (const int*)d_in[18];
    const int*   pos_dst  = (const int*)d_in[19];
    const int*   neg_src  = (const int*)d_in[20];
    const int*   neg_dst  = (const int*)d_in[21];

    float* ws    = (float*)d_ws;
    float* emb   = ws;                        // 8,192,000 f32
    float* hbuf  = emb   + 8192000;           //   655,360 f32
    float* bsumw = hbuf  + 655360;            //    12,800 f32
    float* waddw = bsumw + 12800;             //    25,600 f32
    short* wBw   = (short*)(waddw + 25600);   // 4,915,200 bf16-bits (~45.4 MiB total)

    hipLaunchKernelGGL(prep_kernel, dim3(2048), dim3(256), 0, stream,
                       W_ih, W_hh, b_ih, b_hh, wBw, waddw, bsumw);
    hipLaunchKernelGGL(graph_kernel, dim3(NGRAPH), dim3(64), 0, stream,
                       x0, Wb_pos, bb_pos, Wb_neg, bb_neg,
                       Wd_pos, bd_pos, Wd_neg, bd_neg,
                       pos_src, pos_dst, neg_src, neg_dst, emb);
    hipLaunchKernelGGL(lstm_mfma, dim3(160), dim3(512), 0, stream,
                       emb, add_info, wBw, waddw, bsumw, hx0, cx0, hbuf);
    hipLaunchKernelGGL(final_proj, dim3(80), dim3(256), 0, stream,
                       hbuf, Wf, bf, (float*)d_out);
}